// Round 1
// baseline (4268.089 us; speedup 1.0000x reference)
//
#include <hip/hip_runtime.h>
#include <hip/hip_bf16.h>

// GRU (B=512,T=128,I=128,H=768) + FC(768->256 relu ->10), fp32 in/out.
// Strategy: per-step fused GEMM h|x_t (K=896) x packed W (3 gates, n-gate
// packs hh|ih along K), bf16 3-pass split-precision MFMA (16x16x32),
// 128 stream-ordered step kernels (graph nodes), fp32 FC tail.

typedef unsigned short u16;
typedef float    f32x4   __attribute__((ext_vector_type(4)));
typedef unsigned uint32x4 __attribute__((ext_vector_type(4)));
typedef __bf16   bf16x8  __attribute__((ext_vector_type(8)));

#define MFMA16 __builtin_amdgcn_mfma_f32_16x16x32_bf16

__device__ __forceinline__ float bf2f(u16 u) {
  unsigned v = ((unsigned)u) << 16;
  return __builtin_bit_cast(float, v);
}
__device__ __forceinline__ u16 f2bf(float f) {  // round-to-nearest-even
  unsigned x = __builtin_bit_cast(unsigned, f);
  unsigned r = (x + 0x7fffu + ((x >> 16) & 1u)) >> 16;
  return (u16)r;
}

// ---------------- prep: pack + split weights ----------------
// Wpk rows: [jb 0..31][gate 0..2][col 0..31 (24 real + 8 zero pad)] x [k 0..895]
// gate rows: k<768 -> w_hh[g*768+j][k], k>=768 -> w_ih[g*768+j][k-768]
__global__ __launch_bounds__(256) void k_prep_w(
    const float* __restrict__ w_ih, const float* __restrict__ w_hh,
    u16* __restrict__ Wh, u16* __restrict__ Wl) {
  int idx = blockIdx.x * 256 + threadIdx.x;           // < 3072*896
  int row = idx / 896, k = idx % 896;
  int jb = row / 96, rem = row % 96, g = rem / 32, c = rem % 32;
  float v = 0.f;
  if (c < 24) {
    int grow = g * 768 + jb * 24 + c;
    v = (k < 768) ? w_hh[grow * 768 + k] : w_ih[grow * 128 + (k - 768)];
  }
  u16 h = f2bf(v);
  u16 l = f2bf(v - bf2f(h));
  Wh[idx] = h; Wl[idx] = l;
}

// x[B][T][I] fp32 -> xT[T][B][I] bf16 hi/lo
__global__ __launch_bounds__(256) void k_prep_x(
    const float* __restrict__ x, u16* __restrict__ xh, u16* __restrict__ xl) {
  int idx = blockIdx.x * 256 + threadIdx.x;           // < 512*128*128
  float v = x[idx];
  int b = idx >> 14, t = (idx >> 7) & 127, i = idx & 127;
  int dst = t * 65536 + b * 128 + i;
  u16 h = f2bf(v);
  xh[dst] = h; xl[dst] = f2bf(v - bf2f(h));
}

// ---------------- per-timestep GRU kernel ----------------
// grid 256 = 8 bgroups(64 rows) x 32 colgroups(24 h-cols, padded 32)
// wave w: m-pair p=w&1 (m-tiles 2p,2p+1), col-sub s=w>>1 (16-col half per gate)
__global__ __launch_bounds__(256) void k_step(
    const u16* __restrict__ Wh, const u16* __restrict__ Wl,
    const u16* __restrict__ xh, const u16* __restrict__ xl,
    const u16* __restrict__ hch, const u16* __restrict__ hcl,
    u16* __restrict__ hnh, u16* __restrict__ hnl,
    const float* __restrict__ b_ih, const float* __restrict__ b_hh) {
  // A tile LDS: [buf][hi/lo][kchunk 0..3][row 0..63][8 bf16] -> contiguous per
  // 8-lane phase of ds_read_b128 (bank-conflict-free)
  __shared__ __align__(16) u16 smem[2][2][64 * 32];
  const int tid = threadIdx.x;
  const int lane = tid & 63, wv = tid >> 6;
  const int p = wv & 1, s = wv >> 1;
  const int l15 = lane & 15, lg = lane >> 4;
  const int bid = blockIdx.x;
  const int jb = bid & 31, bg = bid >> 5;   // bid%8 == jb%8 -> 4 jblocks/XCD (W L2-resident)
  const int mbase = bg * 64;
  const int sr = tid & 63, sg = tid >> 6;   // staging row / kchunk

  f32x4 acc[2][4];                           // [m][r,z,nh,ni]
#pragma unroll
  for (int m = 0; m < 2; ++m)
#pragma unroll
    for (int q = 0; q < 4; ++q) acc[m][q] = f32x4{0.f, 0.f, 0.f, 0.f};

  int wrow[3];
#pragma unroll
  for (int g = 0; g < 3; ++g)
    wrow[g] = (jb * 96 + (2 * g + s) * 16 + l15) * 896 + lg * 8;

  const int hsb = (mbase + sr) * 768 + sg * 8;
  const int xsb = (mbase + sr) * 128 + sg * 8;
  const int sof = (sg * 64 + sr) * 8;        // == tid*8 u16 = tid*16B (linear)

  // prologue: stage kt=0 A-tile, load B(kt=0)
  {
    uint32x4 a0 = *(const uint32x4*)(hch + hsb);
    uint32x4 a1 = *(const uint32x4*)(hcl + hsb);
    *(uint32x4*)&smem[0][0][sof] = a0;
    *(uint32x4*)&smem[0][1][sof] = a1;
  }
  bf16x8 Bc[3][2], Bn[3][2];
#pragma unroll
  for (int g = 0; g < 3; ++g) {
    Bc[g][0] = __builtin_bit_cast(bf16x8, *(const uint32x4*)(Wh + wrow[g]));
    Bc[g][1] = __builtin_bit_cast(bf16x8, *(const uint32x4*)(Wl + wrow[g]));
  }
  __syncthreads();

  auto body = [&](int kt, bool nisx, bf16x8 (&Bcur)[3][2], bf16x8 (&Bnxt)[3][2]) {
    const int buf = kt & 1;
    const int ktn = kt + 1;
    uint32x4 sah, sal;
    if (ktn < 28) {                      // A-stage loads first, then B (vmcnt order)
      const u16 *ph, *pl;
      if (ktn < 24) { ph = hch + hsb + ktn * 32; pl = hcl + hsb + ktn * 32; }
      else          { ph = xh + xsb + (ktn - 24) * 32; pl = xl + xsb + (ktn - 24) * 32; }
      sah = *(const uint32x4*)ph;
      sal = *(const uint32x4*)pl;
#pragma unroll
      for (int g = 0; g < 3; ++g) {
        Bnxt[g][0] = __builtin_bit_cast(bf16x8, *(const uint32x4*)(Wh + wrow[g] + ktn * 32));
        Bnxt[g][1] = __builtin_bit_cast(bf16x8, *(const uint32x4*)(Wl + wrow[g] + ktn * 32));
      }
    }
    bf16x8 Ah[2], Al[2];
#pragma unroll
    for (int m = 0; m < 2; ++m) {
      const int offm = (lg * 64 + (2 * p + m) * 16 + l15) * 8;
      Ah[m] = __builtin_bit_cast(bf16x8, *(const uint32x4*)&smem[buf][0][offm]);
      Al[m] = __builtin_bit_cast(bf16x8, *(const uint32x4*)&smem[buf][1][offm]);
    }
    // 3-pass split-precision: AhBh + AhBl + AlBh, pass-major for MFMA interleave
    if (!nisx) {
#pragma unroll
      for (int pass = 0; pass < 3; ++pass)
#pragma unroll
        for (int m = 0; m < 2; ++m) {
          const bf16x8& A = (pass == 2) ? Al[m] : Ah[m];
#pragma unroll
          for (int g = 0; g < 3; ++g) {
            const bf16x8& Bop = (pass == 1) ? Bcur[g][1] : Bcur[g][0];
            if (g == 2) acc[m][2] = MFMA16(A, Bop, acc[m][2], 0, 0, 0);
            else        acc[m][g] = MFMA16(A, Bop, acc[m][g], 0, 0, 0);
          }
        }
    } else {
#pragma unroll
      for (int pass = 0; pass < 3; ++pass)
#pragma unroll
        for (int m = 0; m < 2; ++m) {
          const bf16x8& A = (pass == 2) ? Al[m] : Ah[m];
#pragma unroll
          for (int g = 0; g < 3; ++g) {
            const bf16x8& Bop = (pass == 1) ? Bcur[g][1] : Bcur[g][0];
            if (g == 2) acc[m][3] = MFMA16(A, Bop, acc[m][3], 0, 0, 0);
            else        acc[m][g] = MFMA16(A, Bop, acc[m][g], 0, 0, 0);
          }
        }
    }
    if (ktn < 28) {
      *(uint32x4*)&smem[buf ^ 1][0][sof] = sah;
      *(uint32x4*)&smem[buf ^ 1][1][sof] = sal;
    }
    __syncthreads();
  };

  for (int kk = 0; kk < 6; ++kk) {   // kt 0..23: h-part (acc_nh)
    body(4 * kk + 0, false, Bc, Bn);
    body(4 * kk + 1, false, Bn, Bc);
    body(4 * kk + 2, false, Bc, Bn);
    body(4 * kk + 3, false, Bn, Bc);
  }
  body(24, true, Bc, Bn);            // kt 24..27: x-part (acc_ni)
  body(25, true, Bn, Bc);
  body(26, true, Bc, Bn);
  body(27, true, Bn, Bc);

  // epilogue: gates + h update. C layout: col=lane&15, row=(lane>>4)*4+reg
  const int colp = s * 16 + l15;
  if (colp < 24) {
    const int j = jb * 24 + colp;
    const float bri = b_ih[j],        brh = b_hh[j];
    const float bzi = b_ih[768 + j],  bzh = b_hh[768 + j];
    const float bni = b_ih[1536 + j], bnh = b_hh[1536 + j];
#pragma unroll
    for (int m = 0; m < 2; ++m) {
      const int rb = mbase + (2 * p + m) * 16 + lg * 4;
#pragma unroll
      for (int e = 0; e < 4; ++e) {
        const int row = rb + e;
        float r = 1.f / (1.f + expf(-(acc[m][0][e] + bri + brh)));
        float z = 1.f / (1.f + expf(-(acc[m][1][e] + bzi + bzh)));
        float n = tanhf((acc[m][3][e] + bni) + r * (acc[m][2][e] + bnh));
        float hold = bf2f(hch[row * 768 + j]) + bf2f(hcl[row * 768 + j]);
        float hv = (1.f - z) * n + z * hold;
        u16 uh = f2bf(hv);
        hnh[row * 768 + j] = uh;
        hnl[row * 768 + j] = f2bf(hv - bf2f(uh));
      }
    }
  }
}

// ---------------- FC tail (fp32 exact) ----------------
__global__ __launch_bounds__(256) void k_fc1(
    const u16* __restrict__ hh, const u16* __restrict__ hl,
    const float* __restrict__ w_fc1, const float* __restrict__ b_fc1,
    float* __restrict__ out) {
  __shared__ float a_s[4][768];
  const int tid = threadIdx.x, rb = blockIdx.x * 4;
  for (int i = tid; i < 4 * 768; i += 256) {
    int r = i / 768, k = i % 768;
    a_s[r][k] = bf2f(hh[(rb + r) * 768 + k]) + bf2f(hl[(rb + r) * 768 + k]);
  }
  __syncthreads();
  const int n = tid;
  float a0 = b_fc1[n], a1 = a0, a2 = a0, a3 = a0;
  for (int k = 0; k < 768; k += 4) {
    f32x4 wv = *(const f32x4*)&w_fc1[n * 768 + k];
    f32x4 r0 = *(const f32x4*)&a_s[0][k];
    f32x4 r1 = *(const f32x4*)&a_s[1][k];
    f32x4 r2 = *(const f32x4*)&a_s[2][k];
    f32x4 r3 = *(const f32x4*)&a_s[3][k];
    a0 += r0[0]*wv[0] + r0[1]*wv[1] + r0[2]*wv[2] + r0[3]*wv[3];
    a1 += r1[0]*wv[0] + r1[1]*wv[1] + r1[2]*wv[2] + r1[3]*wv[3];
    a2 += r2[0]*wv[0] + r2[1]*wv[1] + r2[2]*wv[2] + r2[3]*wv[3];
    a3 += r3[0]*wv[0] + r3[1]*wv[1] + r3[2]*wv[2] + r3[3]*wv[3];
  }
  out[(rb + 0) * 256 + n] = fmaxf(a0, 0.f);
  out[(rb + 1) * 256 + n] = fmaxf(a1, 0.f);
  out[(rb + 2) * 256 + n] = fmaxf(a2, 0.f);
  out[(rb + 3) * 256 + n] = fmaxf(a3, 0.f);
}

__global__ __launch_bounds__(256) void k_fc2(
    const float* __restrict__ a, const float* __restrict__ w_fc2,
    const float* __restrict__ b_fc2, float* __restrict__ out) {
  int o = blockIdx.x * 256 + threadIdx.x;
  if (o >= 5120) return;
  int b = o / 10, c = o % 10;
  const float* ar = a + b * 256;
  const float* wr = w_fc2 + c * 256;
  float acc = b_fc2[c];
  for (int k = 0; k < 256; k += 4) {
    f32x4 av = *(const f32x4*)&ar[k];
    f32x4 wv = *(const f32x4*)&wr[k];
    acc += av[0]*wv[0] + av[1]*wv[1] + av[2]*wv[2] + av[3]*wv[3];
  }
  out[o] = acc;
}

// ---------------- host ----------------
extern "C" void kernel_launch(void* const* d_in, const int* in_sizes, int n_in,
                              void* d_out, int out_size, void* d_ws, size_t ws_size,
                              hipStream_t stream) {
  const float* x     = (const float*)d_in[0];
  const float* w_ih  = (const float*)d_in[1];
  const float* w_hh  = (const float*)d_in[2];
  const float* b_ih  = (const float*)d_in[3];
  const float* b_hh  = (const float*)d_in[4];
  const float* w_fc1 = (const float*)d_in[5];
  const float* b_fc1 = (const float*)d_in[6];
  const float* w_fc2 = (const float*)d_in[7];
  const float* b_fc2 = (const float*)d_in[8];
  float* out = (float*)d_out;

  char* ws = (char*)d_ws;
  size_t off = 0;
  auto carve = [&](size_t bytes) {
    char* p = ws + off;
    off += (bytes + 255) & ~(size_t)255;
    return p;
  };
  u16* Wh   = (u16*)carve(3072ull * 896 * 2);
  u16* Wl   = (u16*)carve(3072ull * 896 * 2);
  u16* xTh  = (u16*)carve(128ull * 512 * 128 * 2);
  u16* xTl  = (u16*)carve(128ull * 512 * 128 * 2);
  u16* h0h  = (u16*)carve(512ull * 768 * 2);
  u16* h0l  = (u16*)carve(512ull * 768 * 2);
  u16* h1h  = (u16*)carve(512ull * 768 * 2);
  u16* h1l  = (u16*)carve(512ull * 768 * 2);
  float* fc1o = (float*)carve(512ull * 256 * 4);
  if (off > ws_size) return;  // ~48 MB needed; bail rather than corrupt

  k_prep_w<<<dim3(10752), dim3(256), 0, stream>>>(w_ih, w_hh, Wh, Wl);
  k_prep_x<<<dim3(32768), dim3(256), 0, stream>>>(x, xTh, xTl);
  hipMemsetAsync(h0h, 0, 512ull * 768 * 2 * 2, stream);  // h(0)=0 (h0h+h0l contiguous)

  for (int t = 0; t < 128; ++t) {
    const u16* hch = (t & 1) ? h1h : h0h;
    const u16* hcl = (t & 1) ? h1l : h0l;
    u16* hnh = (t & 1) ? h0h : h1h;
    u16* hnl = (t & 1) ? h0l : h1l;
    k_step<<<dim3(256), dim3(256), 0, stream>>>(
        Wh, Wl, xTh + (size_t)t * 65536, xTl + (size_t)t * 65536,
        hch, hcl, hnh, hnl, b_ih, b_hh);
  }
  k_fc1<<<dim3(128), dim3(256), 0, stream>>>(h0h, h0l, w_fc1, b_fc1, fc1o);
  k_fc2<<<dim3(20), dim3(256), 0, stream>>>(fc1o, w_fc2, b_fc2, out);
}

// Round 2
// 2684.323 us; speedup vs baseline: 1.5900x; 1.5900x over previous
//
#include <hip/hip_runtime.h>
#include <hip/hip_bf16.h>

// GRU (B=512,T=128,I=128,H=768) + FC(768->256 relu ->10), fp32 in/out.
// Round 2: 8-wave k_step (2 waves/SIMD), K=64 bodies, W+A staged to LDS via
// global_load_lds from PRE-SWIZZLED packed layouts (XOR row&15 bank swizzle
// baked in by prep / epilogue), 3-pass bf16 split-precision MFMA 16x16x32.

typedef unsigned short u16;
typedef float    f32x4    __attribute__((ext_vector_type(4)));
typedef unsigned uint32x4 __attribute__((ext_vector_type(4)));
typedef __bf16   bf16x8   __attribute__((ext_vector_type(8)));

#define MFMA16 __builtin_amdgcn_mfma_f32_16x16x32_bf16

#define GLOAD16(gp, lp)                                                        \
  __builtin_amdgcn_global_load_lds(                                            \
      (const __attribute__((address_space(1))) void*)(gp),                     \
      (__attribute__((address_space(3))) void*)(lp), 16, 0, 0)

__device__ __forceinline__ float bf2f(u16 u) {
  unsigned v = ((unsigned)u) << 16;
  return __builtin_bit_cast(float, v);
}
__device__ __forceinline__ u16 f2bf(float f) {  // round-to-nearest-even
  unsigned x = __builtin_bit_cast(unsigned, f);
  unsigned r = (x + 0x7fffu + ((x >> 16) & 1u)) >> 16;
  return (u16)r;
}
__device__ __forceinline__ float sigm(float x) {
  x = fminf(fmaxf(x, -30.f), 30.f);
  return 1.f / (1.f + __expf(-x));
}
__device__ __forceinline__ float tanhx(float x) {
  x = fminf(fmaxf(x, -15.f), 15.f);
  float ex = __expf(2.f * x);
  return (ex - 1.f) / (ex + 1.f);
}

// ---------------- prep: pack + split + swizzle weights ----------------
// Wg[jb 0..31][bt 0..13][row 0..95][c16 0..15][e 0..7] u16
// row = g*32 + c (c<24 real, else 0). logical chunk lc = c16 ^ (row&15);
// hl = lc>>3 (0=hi,1=lo); kc = lc&7; k = bt*64 + kc*8 + e.
// k<768 -> w_hh[g*768+jb*24+c][k], else w_ih[...][k-768].
__global__ __launch_bounds__(256) void k_prep_w(
    const float* __restrict__ w_ih, const float* __restrict__ w_hh,
    u16* __restrict__ Wg) {
  int idx = blockIdx.x * 256 + threadIdx.x;     // < 32*14*96*128 = 5505024
  int e = idx & 7, c16 = (idx >> 3) & 15;
  int r3 = idx >> 7;
  int row = r3 % 96;
  int jbt = r3 / 96;
  int bt = jbt % 14, jb = jbt / 14;
  int lc = c16 ^ (row & 15);
  int hl = lc >> 3, kc = lc & 7;
  int k = bt * 64 + kc * 8 + e;
  int g = row >> 5, c = row & 31;
  float v = 0.f;
  if (c < 24) {
    int grow = g * 768 + jb * 24 + c;
    v = (k < 768) ? w_hh[grow * 768 + k] : w_ih[grow * 128 + (k - 768)];
  }
  u16 h = f2bf(v);
  Wg[idx] = hl ? f2bf(v - bf2f(h)) : h;
}

// xpk[t][bt' 0..1][row 0..511][c16][e] u16 ; i = bt'*64 + kc*8 + e
__global__ __launch_bounds__(256) void k_prep_x(
    const float* __restrict__ x, u16* __restrict__ xpk) {
  int idx = blockIdx.x * 256 + threadIdx.x;     // < 128*2*512*128 = 16777216
  int e = idx & 7, c16 = (idx >> 3) & 15;
  int row = (idx >> 7) & 511;
  int tb = idx >> 16;
  int bt = tb & 1, t = tb >> 1;
  int lc = c16 ^ (row & 15);
  int hl = lc >> 3, kc = lc & 7;
  int i = bt * 64 + kc * 8 + e;
  float v = x[(row * 128 + t) * 128 + i];
  u16 h = f2bf(v);
  xpk[idx] = hl ? f2bf(v - bf2f(h)) : h;
}

// w_fc1T[k][n] = w_fc1[n][k]
__global__ __launch_bounds__(256) void k_prep_fc1t(
    const float* __restrict__ w_fc1, float* __restrict__ wT) {
  int idx = blockIdx.x * 256 + threadIdx.x;     // < 768*256
  int k = idx >> 8, n = idx & 255;
  wT[idx] = w_fc1[n * 768 + k];
}

// ---------------- per-timestep GRU kernel ----------------
// grid 256 = (bg 0..7: 64 rows) x (jb 0..31: 24 h-cols); bid = bg*32+jb
// 512 thr = 8 waves: m4 = wv&3 (16-row m-tile), s = wv>>2 (16-col half/gate)
__global__ __launch_bounds__(512) void k_step(
    const u16* __restrict__ Wg, const u16* __restrict__ xpk_t,
    const u16* __restrict__ hpk_cur, u16* __restrict__ hpk_nxt,
    const float* __restrict__ b_ih, const float* __restrict__ b_hh) {
  // packed tile format: [row][16 chunks of 16B]; chunk c16 holds logical
  // lc = c16 ^ (row&15), lc = hl*8 + kc (kc: 8 u16 of k within body K=64)
  __shared__ __align__(16) u16 sA[2][64 * 128];   // 2 x 16 KB
  __shared__ __align__(16) u16 sW[2][96 * 128];   // 2 x 24 KB
  const int tid = threadIdx.x;
  const int lane = tid & 63, wv = tid >> 6;
  const int m4 = wv & 3, s = wv >> 2;
  const int l15 = lane & 15, lg = lane >> 4;
  const int bid = blockIdx.x;
  const int jb = bid & 31, bg = bid >> 5;   // jb%8 = XCD -> W slice L2-local
  const int mbase = bg * 64;

  f32x4 acc0 = {0.f, 0.f, 0.f, 0.f};  // r
  f32x4 acc1 = {0.f, 0.f, 0.f, 0.f};  // z
  f32x4 acc2 = {0.f, 0.f, 0.f, 0.f};  // n (h-part, bodies 0..11)
  f32x4 acc3 = {0.f, 0.f, 0.f, 0.f};  // n (x-part, bodies 12..13)

  const u16* wbase = Wg + (size_t)(jb * 14) * 12288;

  // ---- prologue: stage body 0 into buf 0 ----
  {
    const u16* ab = hpk_cur + (size_t)mbase * 128;  // bt=0 block
    const u16* wb = wbase;                          // bt=0
    for (int i = wv; i < 16; i += 8)
      GLOAD16(ab + i * 512 + lane * 8, &sA[0][i * 512]);
    for (int j = wv; j < 24; j += 8)
      GLOAD16(wb + j * 512 + lane * 8, &sW[0][j * 512]);
  }
  __syncthreads();

  const int aRow = (m4 * 16 + l15) * 128;
  const int bRow = (s * 16 + l15);

#define MFMA_BLOCK(NACC)                                                       \
  _Pragma("unroll") for (int kk = 0; kk < 2; ++kk)                             \
  _Pragma("unroll") for (int ps = 0; ps < 3; ++ps)                             \
  _Pragma("unroll") for (int g = 0; g < 3; ++g) {                              \
    const bf16x8 Aop = (ps == 2) ? Afr[kk][1] : Afr[kk][0];                    \
    const bf16x8 Bop = (ps == 1) ? Bfr[g][kk][1] : Bfr[g][kk][0];              \
    if (g == 0)      acc0 = MFMA16(Aop, Bop, acc0, 0, 0, 0);                   \
    else if (g == 1) acc1 = MFMA16(Aop, Bop, acc1, 0, 0, 0);                   \
    else             NACC = MFMA16(Aop, Bop, NACC, 0, 0, 0);                   \
  }

  for (int bt = 0; bt < 14; ++bt) {
    const int cb = bt & 1;
    // stage next body into the other buffer (issued early, lands by barrier)
    if (bt < 13) {
      const int nt = bt + 1;
      const u16* ab = (nt < 12)
          ? hpk_cur + (size_t)(nt * 512 + mbase) * 128
          : xpk_t + (size_t)((nt - 12) * 512 + mbase) * 128;
      const u16* wb = wbase + nt * 12288;
      for (int i = wv; i < 16; i += 8)
        GLOAD16(ab + i * 512 + lane * 8, &sA[cb ^ 1][i * 512]);
      for (int j = wv; j < 24; j += 8)
        GLOAD16(wb + j * 512 + lane * 8, &sW[cb ^ 1][j * 512]);
    }
    // fragment reads (swizzled, <=2-way bank aliasing)
    bf16x8 Afr[2][2];     // [kk][hl]
    bf16x8 Bfr[3][2][2];  // [g][kk][hl]
#pragma unroll
    for (int kk = 0; kk < 2; ++kk)
#pragma unroll
      for (int hl = 0; hl < 2; ++hl) {
        const int sw = (((hl << 3) + (kk << 2) + lg) ^ l15) << 3;
        Afr[kk][hl] = *(const bf16x8*)&sA[cb][aRow + sw];
#pragma unroll
        for (int g = 0; g < 3; ++g)
          Bfr[g][kk][hl] = *(const bf16x8*)&sW[cb][(g * 32 + bRow) * 128 + sw];
      }
    if (bt < 12) { MFMA_BLOCK(acc2) }
    else         { MFMA_BLOCK(acc3) }
    __syncthreads();
  }

  // ---- epilogue: gates + h update. C layout: col=lane&15, row=(lane>>4)*4+e
  const int colp = s * 16 + l15;
  if (colp < 24) {
    const int j = jb * 24 + colp;
    const float br = b_ih[j] + b_hh[j];
    const float bz = b_ih[768 + j] + b_hh[768 + j];
    const float bni = b_ih[1536 + j], bnh = b_hh[1536 + j];
    const int bt = j >> 6, kr = j & 63;
    const int kc = kr >> 3, ke = kr & 7;
#pragma unroll
    for (int e = 0; e < 4; ++e) {
      const int row = mbase + m4 * 16 + lg * 4 + e;
      const int hidx = (bt * 512 + row) * 128 + ((kc ^ (row & 15)) << 3) + ke;
      const float hold = bf2f(hpk_cur[hidx]) + bf2f(hpk_cur[hidx ^ 64]);
      const float rg = sigm(acc0[e] + br);
      const float zg = sigm(acc1[e] + bz);
      const float ng = tanhx(acc3[e] + bni + rg * (acc2[e] + bnh));
      const float hv = (1.f - zg) * ng + zg * hold;
      const u16 uh = f2bf(hv);
      hpk_nxt[hidx] = uh;
      hpk_nxt[hidx ^ 64] = f2bf(hv - bf2f(uh));
    }
  }
}

// ---------------- FC tail (fp32) ----------------
__global__ __launch_bounds__(256) void k_fc1(
    const u16* __restrict__ h, const float* __restrict__ wT,
    const float* __restrict__ b1, float* __restrict__ out) {
  __shared__ float a_s[8][768];
  const int tid = threadIdx.x, rb = blockIdx.x * 8;
#pragma unroll
  for (int r = 0; r < 8; ++r) {
    const int row = rb + r, r16 = row & 15;
    for (int k = tid; k < 768; k += 256) {
      const int bt = k >> 6, kr = k & 63;
      const int idx = (bt * 512 + row) * 128 + (((kr >> 3) ^ r16) << 3) + (kr & 7);
      a_s[r][k] = bf2f(h[idx]) + bf2f(h[idx ^ 64]);
    }
  }
  __syncthreads();
  float ac[8];
#pragma unroll
  for (int r = 0; r < 8; ++r) ac[r] = b1[tid];
  for (int k = 0; k < 768; ++k) {
    const float wv = wT[k * 256 + tid];
#pragma unroll
    for (int r = 0; r < 8; ++r) ac[r] += a_s[r][k] * wv;
  }
#pragma unroll
  for (int r = 0; r < 8; ++r)
    out[(rb + r) * 256 + tid] = fmaxf(ac[r], 0.f);
}

__global__ __launch_bounds__(256) void k_fc2(
    const float* __restrict__ a, const float* __restrict__ w_fc2,
    const float* __restrict__ b_fc2, float* __restrict__ out) {
  int o = blockIdx.x * 256 + threadIdx.x;
  if (o >= 5120) return;
  int b = o / 10, c = o % 10;
  const float* ar = a + b * 256;
  const float* wr = w_fc2 + c * 256;
  float acc = b_fc2[c];
  for (int k = 0; k < 256; k += 4) {
    f32x4 av = *(const f32x4*)&ar[k];
    f32x4 wv = *(const f32x4*)&wr[k];
    acc += av[0] * wv[0] + av[1] * wv[1] + av[2] * wv[2] + av[3] * wv[3];
  }
  out[o] = acc;
}

// ---------------- host ----------------
extern "C" void kernel_launch(void* const* d_in, const int* in_sizes, int n_in,
                              void* d_out, int out_size, void* d_ws, size_t ws_size,
                              hipStream_t stream) {
  const float* x     = (const float*)d_in[0];
  const float* w_ih  = (const float*)d_in[1];
  const float* w_hh  = (const float*)d_in[2];
  const float* b_ih  = (const float*)d_in[3];
  const float* b_hh  = (const float*)d_in[4];
  const float* w_fc1 = (const float*)d_in[5];
  const float* b_fc1 = (const float*)d_in[6];
  const float* w_fc2 = (const float*)d_in[7];
  const float* b_fc2 = (const float*)d_in[8];
  float* out = (float*)d_out;

  char* ws = (char*)d_ws;
  size_t off = 0;
  auto carve = [&](size_t bytes) {
    char* p = ws + off;
    off += (bytes + 255) & ~(size_t)255;
    return p;
  };
  u16*   Wg   = (u16*)carve(5505024ull * 2);            // 32*14*96*128 u16
  u16*   xpk  = (u16*)carve(16777216ull * 2);           // 128*2*512*128 u16
  u16*   hpkA = (u16*)carve(786432ull * 2);             // 12*512*128 u16
  u16*   hpkB = (u16*)carve(786432ull * 2);
  float* fc1T = (float*)carve(768ull * 256 * 4);
  float* fc1o = (float*)carve(512ull * 256 * 4);
  if (off > ws_size) return;                            // ~49 MB needed

  k_prep_w<<<dim3(21504), dim3(256), 0, stream>>>(w_ih, w_hh, Wg);
  k_prep_x<<<dim3(65536), dim3(256), 0, stream>>>(x, xpk);
  k_prep_fc1t<<<dim3(768), dim3(256), 0, stream>>>(w_fc1, fc1T);
  hipMemsetAsync(hpkA, 0, 786432ull * 2, stream);       // h(0) = 0

  for (int t = 0; t < 128; ++t) {
    const u16* cur = (t & 1) ? hpkB : hpkA;
    u16* nxt = (t & 1) ? hpkA : hpkB;
    k_step<<<dim3(256), dim3(512), 0, stream>>>(
        Wg, xpk + (size_t)t * 131072, cur, nxt, b_ih, b_hh);
  }
  // t=127 (odd) wrote hpkA
  k_fc1<<<dim3(64), dim3(256), 0, stream>>>(hpkA, fc1T, b_fc1, fc1o);
  k_fc2<<<dim3(20), dim3(256), 0, stream>>>(fc1o, w_fc2, b_fc2, out);
}

// Round 3
// 2275.306 us; speedup vs baseline: 1.8758x; 1.1798x over previous
//
#include <hip/hip_runtime.h>
#include <hip/hip_bf16.h>

// GRU (B=512,T=128,I=128,H=768) + FC(768->256 relu ->10), fp32 in/out.
// Round 3: 8-wave k_step with wave layout (mg x sg x kg) — K split across kg
// pairs (LDS traffic -56%), 3-buffer counted-vmcnt pipeline (stage 2 bodies
// ahead, raw s_barrier, vmcnt(4) never 0 mid-loop), 2-pass split precision
// (AhBh + AlBh; W low bits dropped -> W staging halved). FC tail rewritten.

typedef unsigned short u16;
typedef float    f32x4    __attribute__((ext_vector_type(4)));
typedef unsigned uint32x4 __attribute__((ext_vector_type(4)));
typedef __bf16   bf16x8   __attribute__((ext_vector_type(8)));

#define MFMA16 __builtin_amdgcn_mfma_f32_16x16x32_bf16

#define GLOAD16(gp, lp)                                                        \
  __builtin_amdgcn_global_load_lds(                                            \
      (const __attribute__((address_space(1))) void*)(gp),                     \
      (__attribute__((address_space(3))) void*)(lp), 16, 0, 0)

__device__ __forceinline__ float bf2f(u16 u) {
  unsigned v = ((unsigned)u) << 16;
  return __builtin_bit_cast(float, v);
}
__device__ __forceinline__ u16 f2bf(float f) {  // round-to-nearest-even
  unsigned x = __builtin_bit_cast(unsigned, f);
  unsigned r = (x + 0x7fffu + ((x >> 16) & 1u)) >> 16;
  return (u16)r;
}
__device__ __forceinline__ float sigm(float x) {
  x = fminf(fmaxf(x, -30.f), 30.f);
  return 1.f / (1.f + __expf(-x));
}
__device__ __forceinline__ float tanhx(float x) {
  x = fminf(fmaxf(x, -15.f), 15.f);
  float ex = __expf(2.f * x);
  return (ex - 1.f) / (ex + 1.f);
}

// ---------------- prep: pack + swizzle weights (hi bf16 only) ----------------
// Wg[jb 0..31][bt 0..13][row 0..95][c8 0..7][e 0..7] u16; row = g*32+c
// (c<24 real). slot c8 holds kc = c8 ^ (row&7); k = bt*64 + kc*8 + e.
// k<768 -> w_hh[g*768+jb*24+c][k], else w_ih[...][k-768].
__global__ __launch_bounds__(256) void k_prep_w(
    const float* __restrict__ w_ih, const float* __restrict__ w_hh,
    u16* __restrict__ Wg) {
  int idx = blockIdx.x * 256 + threadIdx.x;     // < 32*14*96*64 = 2752512
  int e = idx & 7, c8 = (idx >> 3) & 7;
  int r3 = idx >> 6;
  int row = r3 % 96;
  int jbt = r3 / 96;
  int bt = jbt % 14, jb = jbt / 14;
  int kc = c8 ^ (row & 7);
  int k = bt * 64 + kc * 8 + e;
  int g = row >> 5, c = row & 31;
  float v = 0.f;
  if (c < 24) {
    int grow = g * 768 + jb * 24 + c;
    v = (k < 768) ? w_hh[grow * 768 + k] : w_ih[grow * 128 + (k - 768)];
  }
  Wg[idx] = f2bf(v);
}

// xpk[t][bt' 0..1][row 0..511][c16][e] u16 (hi/lo 16-chunk, row&15 XOR)
__global__ __launch_bounds__(256) void k_prep_x(
    const float* __restrict__ x, u16* __restrict__ xpk) {
  int idx = blockIdx.x * 256 + threadIdx.x;     // < 128*2*512*128 = 16777216
  int e = idx & 7, c16 = (idx >> 3) & 15;
  int row = (idx >> 7) & 511;
  int tb = idx >> 16;
  int bt = tb & 1, t = tb >> 1;
  int lc = c16 ^ (row & 15);
  int hl = lc >> 3, kc = lc & 7;
  int i = bt * 64 + kc * 8 + e;
  float v = x[(row * 128 + t) * 128 + i];
  u16 h = f2bf(v);
  xpk[idx] = hl ? f2bf(v - bf2f(h)) : h;
}

// w_fc1T[k][n] = w_fc1[n][k]
__global__ __launch_bounds__(256) void k_prep_fc1t(
    const float* __restrict__ w_fc1, float* __restrict__ wT) {
  int idx = blockIdx.x * 256 + threadIdx.x;     // < 768*256
  int k = idx >> 8, n = idx & 255;
  wT[idx] = w_fc1[n * 768 + k];
}

// ---------------- per-timestep GRU kernel ----------------
// grid 256 = (bg 0..7: 64 rows) x (jb 0..31: 24 h-cols); bid = bg*32+jb
// 512 thr = 8 waves: mg=wv>>2 (2 m-tiles), sg=(wv>>1)&1 (16-col half/gate),
// kg=wv&1 (K half of each 64-K body). kg pairs reduced at end via LDS.
__global__ __launch_bounds__(512) void k_step(
    const u16* __restrict__ Wg, const u16* __restrict__ xpk_t,
    const u16* __restrict__ hpk_cur, u16* __restrict__ hpk_nxt,
    const float* __restrict__ b_ih, const float* __restrict__ b_hh) {
  __shared__ __align__(16) u16 sA[3][64 * 128];   // 3 x 16 KB (h/x: hi+lo)
  __shared__ __align__(16) u16 sW[3][96 * 64];    // 3 x 12 KB (W: hi only)
  const int tid = threadIdx.x;
  const int lane = tid & 63, wv = tid >> 6;
  const int mg = wv >> 2, sg = (wv >> 1) & 1, kg = wv & 1;
  const int l15 = lane & 15, lg = lane >> 4;
  const int bid = blockIdx.x;
  const int jb = bid & 31, bg = bid >> 5;   // jb%8 = XCD -> W slice L2-local
  const int mbase = bg * 64;

  f32x4 acc[2][4];                           // [mi][r,z,nh,nx]
#pragma unroll
  for (int mi = 0; mi < 2; ++mi)
#pragma unroll
    for (int q = 0; q < 4; ++q) acc[mi][q] = f32x4{0.f, 0.f, 0.f, 0.f};

  const u16* wbase = Wg + (size_t)jb * 86016;           // 14*6144
  const u16* hA = hpk_cur + (size_t)mbase * 128;
  const u16* xA = xpk_t + (size_t)mbase * 128;

  // stage one body's 28 KB as 28 x 1KB chunks; waves 0..6 take 4 each.
  auto stage = [&](int nt, int nbuf) {
    if (wv < 7) {
      const u16* ab = (nt < 12) ? hA + nt * 65536 : xA + (nt - 12) * 65536;
      const u16* wb = wbase + nt * 6144;
#pragma unroll
      for (int c = 0; c < 4; ++c) {
        const int ch = wv * 4 + c;
        if (ch < 16) GLOAD16(ab + ch * 512 + lane * 8, &sA[nbuf][ch * 512]);
        else GLOAD16(wb + (ch - 16) * 512 + lane * 8, &sW[nbuf][(ch - 16) * 512]);
      }
    }
  };

  // prologue: stage bodies 0,1
  stage(0, 0);
  stage(1, 1);
  if (wv < 7) asm volatile("s_waitcnt vmcnt(4)" ::: "memory");
  asm volatile("" ::: "memory");
  __builtin_amdgcn_s_barrier();
  asm volatile("" ::: "memory");

#pragma unroll
  for (int bt = 0; bt < 14; ++bt) {
    const int buf = bt % 3;
    if (bt + 2 < 14) stage(bt + 2, (bt + 2) % 3);
    // fragment reads (A: 16-chunk row&15 XOR; W: 8-chunk row&7 XOR)
    bf16x8 Ahf[2], Alf[2], Bf[3];
#pragma unroll
    for (int mi = 0; mi < 2; ++mi) {
      const int ar = (mg * 32 + mi * 16 + l15) * 128;
      const int swH = (((kg << 2) + lg) ^ l15) << 3;
      const int swL = ((8 + (kg << 2) + lg) ^ l15) << 3;
      Ahf[mi] = *(const bf16x8*)&sA[buf][ar + swH];
      Alf[mi] = *(const bf16x8*)&sA[buf][ar + swL];
    }
#pragma unroll
    for (int g = 0; g < 3; ++g) {
      const int br = (g * 32 + sg * 16 + l15) * 64;
      const int c8 = (((kg << 2) + lg) ^ (l15 & 7)) << 3;
      Bf[g] = *(const bf16x8*)&sW[buf][br + c8];
    }
    __builtin_amdgcn_s_setprio(1);
#pragma unroll
    for (int ps = 0; ps < 2; ++ps)
#pragma unroll
      for (int mi = 0; mi < 2; ++mi)
#pragma unroll
        for (int g = 0; g < 3; ++g) {
          const bf16x8 Aop = ps ? Alf[mi] : Ahf[mi];
          if (g == 0)      acc[mi][0] = MFMA16(Aop, Bf[0], acc[mi][0], 0, 0, 0);
          else if (g == 1) acc[mi][1] = MFMA16(Aop, Bf[1], acc[mi][1], 0, 0, 0);
          else if (bt < 12) acc[mi][2] = MFMA16(Aop, Bf[2], acc[mi][2], 0, 0, 0);
          else             acc[mi][3] = MFMA16(Aop, Bf[2], acc[mi][3], 0, 0, 0);
        }
    __builtin_amdgcn_s_setprio(0);
    if (bt < 13) {
      if (wv < 7) {
        if (bt < 12) asm volatile("s_waitcnt vmcnt(4)" ::: "memory");
        else         asm volatile("s_waitcnt vmcnt(0)" ::: "memory");
      }
      asm volatile("" ::: "memory");
      __builtin_amdgcn_s_barrier();
      asm volatile("" ::: "memory");
    }
  }

  // ---- kg-pair accumulator reduction via LDS (reuse sA as scratch) ----
  __syncthreads();
  f32x4* sc = (f32x4*)&sA[0][0];                 // 32 KB scratch
  if (kg == 1) {
#pragma unroll
    for (int mi = 0; mi < 2; ++mi)
#pragma unroll
      for (int q = 0; q < 4; ++q)
        sc[(((wv >> 1) * 8) + mi * 4 + q) * 64 + lane] = acc[mi][q];
  }
  __syncthreads();
  if (kg == 1) return;
#pragma unroll
  for (int mi = 0; mi < 2; ++mi)
#pragma unroll
    for (int q = 0; q < 4; ++q) {
      f32x4 part = sc[(((wv >> 1) * 8) + mi * 4 + q) * 64 + lane];
      acc[mi][q] += part;
    }

  // ---- epilogue: gates + h update. C layout: col=lane&15, row=(lane>>4)*4+e
  const int colp = sg * 16 + l15;
  if (colp < 24) {
    const int j = jb * 24 + colp;
    const float br = b_ih[j] + b_hh[j];
    const float bz = b_ih[768 + j] + b_hh[768 + j];
    const float bni = b_ih[1536 + j], bnh = b_hh[1536 + j];
    const int bt = j >> 6, kr = j & 63;
    const int kc = kr >> 3, ke = kr & 7;
#pragma unroll
    for (int mi = 0; mi < 2; ++mi)
#pragma unroll
      for (int e = 0; e < 4; ++e) {
        const int row = mbase + (mg * 2 + mi) * 16 + lg * 4 + e;
        const int hidx = (bt * 512 + row) * 128 + ((kc ^ (row & 15)) << 3) + ke;
        const float hold = bf2f(hpk_cur[hidx]) + bf2f(hpk_cur[hidx ^ 64]);
        const float rg = sigm(acc[mi][0][e] + br);
        const float zg = sigm(acc[mi][1][e] + bz);
        const float ng = tanhx(acc[mi][3][e] + bni + rg * (acc[mi][2][e] + bnh));
        const float hv = (1.f - zg) * ng + zg * hold;
        const u16 uh = f2bf(hv);
        hpk_nxt[hidx] = uh;
        hpk_nxt[hidx ^ 64] = f2bf(hv - bf2f(uh));
      }
  }
}

// ---------------- FC tail (fp32) ----------------
// 128 blocks x 4 rows; n = tid; unroll-8 k loop, coalesced wT loads.
__global__ __launch_bounds__(256) void k_fc1(
    const u16* __restrict__ h, const float* __restrict__ wT,
    const float* __restrict__ b1, float* __restrict__ out) {
  __shared__ float a_s[4][768];
  const int tid = threadIdx.x, rb = blockIdx.x * 4;
#pragma unroll
  for (int r = 0; r < 4; ++r) {
    const int row = rb + r, r16 = row & 15;
    for (int k = tid; k < 768; k += 256) {
      const int bt = k >> 6, kr = k & 63;
      const int idx = (bt * 512 + row) * 128 + (((kr >> 3) ^ r16) << 3) + (kr & 7);
      a_s[r][k] = bf2f(h[idx]) + bf2f(h[idx ^ 64]);
    }
  }
  __syncthreads();
  const int n = tid;
  float ac0 = b1[n], ac1 = ac0, ac2 = ac0, ac3 = ac0;
  for (int k0 = 0; k0 < 768; k0 += 8) {
    float w[8];
#pragma unroll
    for (int u = 0; u < 8; ++u) w[u] = wT[(k0 + u) * 256 + n];
#pragma unroll
    for (int u = 0; u < 8; ++u) {
      ac0 += a_s[0][k0 + u] * w[u];
      ac1 += a_s[1][k0 + u] * w[u];
      ac2 += a_s[2][k0 + u] * w[u];
      ac3 += a_s[3][k0 + u] * w[u];
    }
  }
  out[(rb + 0) * 256 + n] = fmaxf(ac0, 0.f);
  out[(rb + 1) * 256 + n] = fmaxf(ac1, 0.f);
  out[(rb + 2) * 256 + n] = fmaxf(ac2, 0.f);
  out[(rb + 3) * 256 + n] = fmaxf(ac3, 0.f);
}

// 128 blocks x 4 waves; one wave per batch row, shfl-reduce over K=256.
__global__ __launch_bounds__(256) void k_fc2(
    const float* __restrict__ a, const float* __restrict__ w_fc2,
    const float* __restrict__ b_fc2, float* __restrict__ out) {
  const int lane = threadIdx.x & 63, w = threadIdx.x >> 6;
  const int b = blockIdx.x * 4 + w;
  const f32x4 av = ((const f32x4*)(a + b * 256))[lane];
#pragma unroll
  for (int c = 0; c < 10; ++c) {
    const f32x4 wv = ((const f32x4*)(w_fc2 + c * 256))[lane];
    float s = av[0] * wv[0] + av[1] * wv[1] + av[2] * wv[2] + av[3] * wv[3];
#pragma unroll
    for (int off = 32; off > 0; off >>= 1) s += __shfl_xor(s, off);
    if (lane == 0) out[b * 10 + c] = s + b_fc2[c];
  }
}

// ---------------- host ----------------
extern "C" void kernel_launch(void* const* d_in, const int* in_sizes, int n_in,
                              void* d_out, int out_size, void* d_ws, size_t ws_size,
                              hipStream_t stream) {
  const float* x     = (const float*)d_in[0];
  const float* w_ih  = (const float*)d_in[1];
  const float* w_hh  = (const float*)d_in[2];
  const float* b_ih  = (const float*)d_in[3];
  const float* b_hh  = (const float*)d_in[4];
  const float* w_fc1 = (const float*)d_in[5];
  const float* b_fc1 = (const float*)d_in[6];
  const float* w_fc2 = (const float*)d_in[7];
  const float* b_fc2 = (const float*)d_in[8];
  float* out = (float*)d_out;

  char* ws = (char*)d_ws;
  size_t off = 0;
  auto carve = [&](size_t bytes) {
    char* p = ws + off;
    off += (bytes + 255) & ~(size_t)255;
    return p;
  };
  u16*   Wg   = (u16*)carve(2752512ull * 2);            // 32*14*96*64 u16
  u16*   xpk  = (u16*)carve(16777216ull * 2);           // 128*2*512*128 u16
  u16*   hpkA = (u16*)carve(786432ull * 2);             // 12*512*128 u16
  u16*   hpkB = (u16*)carve(786432ull * 2);
  float* fc1T = (float*)carve(768ull * 256 * 4);
  float* fc1o = (float*)carve(512ull * 256 * 4);
  if (off > ws_size) return;                            // ~44 MB needed

  k_prep_w<<<dim3(10752), dim3(256), 0, stream>>>(w_ih, w_hh, Wg);
  k_prep_x<<<dim3(65536), dim3(256), 0, stream>>>(x, xpk);
  k_prep_fc1t<<<dim3(768), dim3(256), 0, stream>>>(w_fc1, fc1T);
  hipMemsetAsync(hpkA, 0, 786432ull * 2, stream);       // h(0) = 0

  for (int t = 0; t < 128; ++t) {
    const u16* cur = (t & 1) ? hpkB : hpkA;
    u16* nxt = (t & 1) ? hpkA : hpkB;
    k_step<<<dim3(256), dim3(512), 0, stream>>>(
        Wg, xpk + (size_t)t * 131072, cur, nxt, b_ih, b_hh);
  }
  // t=127 (odd) wrote hpkA
  k_fc1<<<dim3(128), dim3(256), 0, stream>>>(hpkA, fc1T, b_fc1, fc1o);
  k_fc2<<<dim3(128), dim3(256), 0, stream>>>(fc1o, w_fc2, b_fc2, out);
}